// Round 2
// baseline (332.940 us; speedup 1.0000x reference)
//
#include <hip/hip_runtime.h>
#include <hip/hip_fp16.h>
#include <math.h>

#define N_NODES 50000
#define N_EDGES 1600000
#define NFEAT 256
#define NHID 128
#define NCLASS 40

#define BSHIFT 7
#define NBUCK 391            // ceil(50000 / 128)
#define CAP 5120             // per-bucket capacity (mean 4092)
#define EPB 4096             // edges per binA block -> 391 blocks

#define PL1 ((size_t)N_NODES * 32)   // halves per h1 feature-plane (64 B rows)
#define PL2A ((size_t)N_NODES * 32)  // halves offset of h2 plane1 (classes 32..39)

typedef _Float16 f16x8 __attribute__((ext_vector_type(8)));
typedef float f32x4 __attribute__((ext_vector_type(4)));

// ---------------- pass A: coarse binning by dst>>7 ----------------
__global__ __launch_bounds__(256) void k_binA(const int* __restrict__ src,
                                              const int* __restrict__ dst,
                                              int* __restrict__ gcur,
                                              unsigned int* __restrict__ packed) {
    __shared__ int lhist[NBUCK];
    __shared__ int lbase[NBUCK];
    __shared__ int lcur[NBUCK];
    int t = threadIdx.x;
    for (int i = t; i < NBUCK; i += 256) { lhist[i] = 0; lcur[i] = 0; }
    __syncthreads();
    int e0 = blockIdx.x * EPB;
    int e1 = min(e0 + EPB, N_EDGES);
    for (int e = e0 + t; e < e1; e += 256) {
        int b = dst[e] >> BSHIFT;
        atomicAdd(&lhist[b], 1);
    }
    __syncthreads();
    for (int i = t; i < NBUCK; i += 256)
        lbase[i] = atomicAdd(&gcur[i], lhist[i]);
    __syncthreads();
    for (int e = e0 + t; e < e1; e += 256) {
        int d = dst[e];
        int b = d >> BSHIFT;
        int r = atomicAdd(&lcur[b], 1);
        int pos = lbase[b] + r;
        if (pos < CAP)
            packed[(size_t)b * CAP + pos] =
                ((unsigned int)src[e] << BSHIFT) | (unsigned int)(d & 127);
    }
}

// ---------------- pass B: in-LDS fine sort per bucket + CSR metadata ----------------
__global__ __launch_bounds__(256) void k_binB(const int* __restrict__ gcur,
                                              const unsigned int* __restrict__ packed,
                                              int* __restrict__ esrc,
                                              int* __restrict__ row_beg,
                                              int* __restrict__ row_cnt,
                                              float* __restrict__ dinv) {
    __shared__ unsigned int sp[CAP];     // 20 KB
    __shared__ int hist[128];
    __shared__ int scan[128];
    __shared__ int cur[128];
    int b = blockIdx.x;
    int t = threadIdx.x;
    int cnt = min(gcur[b], CAP);
    if (t < 128) { hist[t] = 0; cur[t] = 0; }
    __syncthreads();
    const unsigned int* pin = packed + (size_t)b * CAP;
    for (int i = t; i < cnt; i += 256) {
        unsigned int w = pin[i];
        sp[i] = w;
        atomicAdd(&hist[w & 127], 1);
    }
    __syncthreads();
    if (t == 0) {
        int s = 0;
        for (int i = 0; i < 128; i++) { scan[i] = s; s += hist[i]; }
    }
    __syncthreads();
    for (int i = t; i < cnt; i += 256) {
        unsigned int w = sp[i];
        int dl = (int)(w & 127u);
        int r = atomicAdd(&cur[dl], 1);
        esrc[(size_t)b * CAP + scan[dl] + r] = (int)(w >> BSHIFT);
    }
    if (t < 128) {
        int node = b * 128 + t;
        if (node < N_NODES) {
            row_beg[node] = b * CAP + scan[t];
            row_cnt[node] = hist[t];
            dinv[node] = rsqrtf((float)(hist[t] + 1));
        }
    }
}

// ---------------- prep: W transposes to fp16 + gcur zeroing ----------------
__global__ __launch_bounds__(256) void k_prep(const float* __restrict__ W1,
                                              const float* __restrict__ W2,
                                              __half* __restrict__ w1t,
                                              __half* __restrict__ w2t,
                                              int* __restrict__ gcur) {
    int t = blockIdx.x * 256 + threadIdx.x;
    if (t < NBUCK) gcur[t] = 0;
    if (t < 128 * 256) {
        int n = t >> 8, k = t & 255;
        w1t[t] = __float2half(W1[k * NHID + n]);
    }
    if (t < 48 * 128) {
        int n = t >> 7, k = t & 127;
        w2t[t] = __float2half(n < NCLASS ? W2[k * NCLASS + n] : 0.0f);
    }
}

// ---------------- GEMM1 (MFMA): h1 planes (4 x 32 feat, 64B rows) = x @ W1 ----------------
#define G1_LDA 72
#define G1_LDB 72
#define G1_LDE 136
__global__ __launch_bounds__(256) void k_gemm1(const float* __restrict__ x,
                                               const __half* __restrict__ w1t,
                                               __half* __restrict__ h1h) {
    __shared__ __half smem[64 * G1_LDA + 128 * G1_LDB];   // 27.6 KB
    __half* sA = smem;
    __half* sB = smem + 64 * G1_LDA;
    int t = threadIdx.x;
    int rbase = blockIdx.x * 64;
    int lane = t & 63, wv = t >> 6;
    int m = lane & 15, quad = lane >> 4;
    f32x4 acc[8];
    #pragma unroll
    for (int i = 0; i < 8; i++) acc[i] = (f32x4)0.0f;

    int arow = t >> 2, aseg = t & 3;
    int grow = rbase + arow;
    bool avalid = grow < N_NODES;
    int bn = t >> 1, bseg = t & 1;

    for (int k0 = 0; k0 < NFEAT; k0 += 64) {
        const float4* gs = (const float4*)(x + (size_t)grow * NFEAT + k0 + aseg * 16);
        __half* ad = sA + arow * G1_LDA + aseg * 16;
        #pragma unroll
        for (int i = 0; i < 4; i++) {
            float4 v = avalid ? gs[i] : make_float4(0.f, 0.f, 0.f, 0.f);
            __half2 h0 = __float22half2_rn(make_float2(v.x, v.y));
            __half2 h1 = __float22half2_rn(make_float2(v.z, v.w));
            uint2 st;
            st.x = __builtin_bit_cast(unsigned int, h0);
            st.y = __builtin_bit_cast(unsigned int, h1);
            *(uint2*)(ad + i * 4) = st;
        }
        const uint4* ws4 = (const uint4*)(w1t + bn * NFEAT + k0 + bseg * 32);
        uint4* bd = (uint4*)(sB + bn * G1_LDB + bseg * 32);
        #pragma unroll
        for (int i = 0; i < 4; i++) bd[i] = ws4[i];
        __syncthreads();
        #pragma unroll
        for (int kk = 0; kk < 64; kk += 32) {
            f16x8 af = *(const f16x8*)(sA + (wv * 16 + m) * G1_LDA + kk + quad * 8);
            #pragma unroll
            for (int t8 = 0; t8 < 8; t8++) {
                f16x8 bf = *(const f16x8*)(sB + (t8 * 16 + m) * G1_LDB + kk + quad * 8);
                acc[t8] = __builtin_amdgcn_mfma_f32_16x16x32_f16(af, bf, acc[t8], 0, 0, 0);
            }
        }
        __syncthreads();
    }
    __half* eb = smem;
    #pragma unroll
    for (int t8 = 0; t8 < 8; t8++) {
        #pragma unroll
        for (int r = 0; r < 4; r++)
            eb[(wv * 16 + quad * 4 + r) * G1_LDE + t8 * 16 + m] = __float2half(acc[t8][r]);
    }
    __syncthreads();
    if (avalid) {
        const uint4* es = (const uint4*)(eb + arow * G1_LDE + aseg * 32);
        // plane-major: plane aseg holds features [aseg*32, aseg*32+32) as 64B rows
        uint4* od = (uint4*)(h1h + (size_t)aseg * PL1 + (size_t)grow * 32);
        #pragma unroll
        for (int i = 0; i < 4; i++) od[i] = es[i];
    }
}

// ---------------- GEMM2 (MFMA): h2 planes = h1p @ W2 ----------------
#define G2_LDA 136
#define G2_LDB 136
#define G2_LDE 72
__global__ __launch_bounds__(256) void k_gemm2(const __half* __restrict__ h1p,
                                               const __half* __restrict__ w2t,
                                               __half* __restrict__ h2p) {
    __shared__ __half smem[64 * G2_LDA + 48 * G2_LDB];  // 30.5 KB
    __half* sA = smem;
    __half* sB = smem + 64 * G2_LDA;
    int t = threadIdx.x;
    int rbase = blockIdx.x * 64;
    int lane = t & 63, wv = t >> 6;
    int m = lane & 15, quad = lane >> 4;
    f32x4 acc[3];
    #pragma unroll
    for (int i = 0; i < 3; i++) acc[i] = (f32x4)0.0f;

    int arow = t >> 2, aseg = t & 3;
    int grow = rbase + arow;
    bool avalid = grow < N_NODES;

    #pragma unroll
    for (int i = 0; i < 3; i++) {
        int idx = t + i * 256;
        int n = idx >> 4, seg = idx & 15;
        *(uint4*)(sB + n * G2_LDB + seg * 8) = *(const uint4*)(w2t + n * NHID + seg * 8);
    }
    {
        const uint4* gs = (const uint4*)(h1p + (size_t)grow * NHID + aseg * 32);
        uint4* ad = (uint4*)(sA + arow * G2_LDA + aseg * 32);
        uint4 z; z.x = z.y = z.z = z.w = 0;
        #pragma unroll
        for (int i = 0; i < 4; i++) ad[i] = avalid ? gs[i] : z;
    }
    __syncthreads();
    #pragma unroll
    for (int kk = 0; kk < 128; kk += 32) {
        f16x8 af = *(const f16x8*)(sA + (wv * 16 + m) * G2_LDA + kk + quad * 8);
        #pragma unroll
        for (int t3 = 0; t3 < 3; t3++) {
            f16x8 bf = *(const f16x8*)(sB + (t3 * 16 + m) * G2_LDB + kk + quad * 8);
            acc[t3] = __builtin_amdgcn_mfma_f32_16x16x32_f16(af, bf, acc[t3], 0, 0, 0);
        }
    }
    __syncthreads();
    __half* eb = smem;
    #pragma unroll
    for (int t3 = 0; t3 < 3; t3++) {
        #pragma unroll
        for (int r = 0; r < 4; r++)
            eb[(wv * 16 + quad * 4 + r) * G2_LDE + t3 * 16 + m] = __float2half(acc[t3][r]);
    }
    __syncthreads();
    // plane0: classes 0..31 as 64B rows; plane1: classes 32..39 as 16B rows
    #pragma unroll
    for (int i = 0; i < 2; i++) {
        int idx = t + i * 256;
        int row = idx >> 3, seg = idx & 7;
        int gr = rbase + row;
        if (gr < N_NODES && seg <= 4) {
            uint4 v = *(const uint4*)(eb + row * G2_LDE + seg * 8);
            if (seg < 4) ((uint4*)h2p)[(size_t)gr * 4 + seg] = v;
            else        ((uint4*)(h2p + PL2A))[gr] = v;
        }
    }
}

__device__ __forceinline__ void acc8f(float* acc, uint4 v, float d) {
    float2 a0 = __half22float2(__builtin_bit_cast(__half2, v.x));
    float2 a1 = __half22float2(__builtin_bit_cast(__half2, v.y));
    float2 a2 = __half22float2(__builtin_bit_cast(__half2, v.z));
    float2 a3 = __half22float2(__builtin_bit_cast(__half2, v.w));
    acc[0] = fmaf(a0.x, d, acc[0]); acc[1] = fmaf(a0.y, d, acc[1]);
    acc[2] = fmaf(a1.x, d, acc[2]); acc[3] = fmaf(a1.y, d, acc[3]);
    acc[4] = fmaf(a2.x, d, acc[4]); acc[5] = fmaf(a2.y, d, acc[5]);
    acc[6] = fmaf(a3.x, d, acc[6]); acc[7] = fmaf(a3.y, d, acc[7]);
}

// ---------------- agg1: 4 feature-plane epochs, L2-resident 3.2MB table each ----------------
// grid = 50000 blocks: blocks [s*12500, (s+1)*12500) process plane s (split-major order)
__global__ __launch_bounds__(256, 8) void k_agg1(const __half* __restrict__ h1h,
                                                 const float* __restrict__ dinv,
                                                 const int* __restrict__ row_beg,
                                                 const int* __restrict__ row_cnt,
                                                 const int* __restrict__ esrc,
                                                 const float* __restrict__ b1,
                                                 const float* __restrict__ mask,
                                                 __half* __restrict__ h1p) {
    int s = blockIdx.x / 12500;                        // feature plane 0..3
    int i = (blockIdx.x % 12500) * 4 + (threadIdx.x >> 6);
    int lane = threadIdx.x & 63;
    int g = lane >> 2;        // group 0..15, one edge per group per gather
    int fl = lane & 3;        // 16B chunk within 64B row
    const uint4* hp = (const uint4*)(h1h + (size_t)s * PL1);
    float di = dinv[i];
    __half2 hacc[4];
    __half2 hz = __half2half2(__float2half(0.0f));
    hacc[0] = hz; hacc[1] = hz; hacc[2] = hz; hacc[3] = hz;
    int s0 = row_beg[i], cnt = row_cnt[i];
    for (int base = 0; base < cnt; base += 64) {
        int idx = base + lane;
        int sv = (idx < cnt) ? esrc[s0 + idx] : 0;
        float dv = (idx < cnt) ? dinv[sv] : 0.0f;
        int ss[4]; __half2 dd[4]; uint4 vv[4];
        #pragma unroll
        for (int k = 0; k < 4; k++) {
            int jx = k * 16 + g;
            ss[k] = __shfl(sv, jx);
            dd[k] = __half2half2(__float2half(__shfl(dv, jx)));
        }
        #pragma unroll
        for (int k = 0; k < 4; k++) vv[k] = hp[(size_t)ss[k] * 4 + fl];
        #pragma unroll
        for (int k = 0; k < 4; k++) {
            hacc[0] = __hfma2(__builtin_bit_cast(__half2, vv[k].x), dd[k], hacc[0]);
            hacc[1] = __hfma2(__builtin_bit_cast(__half2, vv[k].y), dd[k], hacc[1]);
            hacc[2] = __hfma2(__builtin_bit_cast(__half2, vv[k].z), dd[k], hacc[2]);
            hacc[3] = __hfma2(__builtin_bit_cast(__half2, vv[k].w), dd[k], hacc[3]);
        }
    }
    // reduce across 16 groups (strides 4..32)
    #pragma unroll
    for (int d = 4; d <= 32; d <<= 1) {
        #pragma unroll
        for (int r = 0; r < 4; r++) {
            unsigned int u = __shfl_xor(__builtin_bit_cast(unsigned int, hacc[r]), d);
            hacc[r] = __hadd2(hacc[r], __builtin_bit_cast(__half2, u));
        }
    }
    if (g == 0) {   // lanes 0..3 hold features [s*32 + fl*8, +8)
        float acc[8];
        #pragma unroll
        for (int r = 0; r < 4; r++) {
            float2 f = __half22float2(hacc[r]);
            acc[2 * r] = f.x; acc[2 * r + 1] = f.y;
        }
        uint4 sv4 = hp[(size_t)i * 4 + fl];   // self row chunk
        acc8f(acc, sv4, di);
        const float4* bp = (const float4*)(b1 + s * 32 + fl * 8);
        float4 bb0 = bp[0];
        float4 bb1 = bp[1];
        const float4* mrow = (const float4*)(mask + (size_t)i * NHID + s * 32 + fl * 8);
        float4 mm0 = mrow[0];
        float4 mm1 = mrow[1];
        float o0 = fmaxf(fmaf(acc[0], di, bb0.x), 0.f) * mm0.x;
        float o1 = fmaxf(fmaf(acc[1], di, bb0.y), 0.f) * mm0.y;
        float o2 = fmaxf(fmaf(acc[2], di, bb0.z), 0.f) * mm0.z;
        float o3 = fmaxf(fmaf(acc[3], di, bb0.w), 0.f) * mm0.w;
        float o4 = fmaxf(fmaf(acc[4], di, bb1.x), 0.f) * mm1.x;
        float o5 = fmaxf(fmaf(acc[5], di, bb1.y), 0.f) * mm1.y;
        float o6 = fmaxf(fmaf(acc[6], di, bb1.z), 0.f) * mm1.z;
        float o7 = fmaxf(fmaf(acc[7], di, bb1.w), 0.f) * mm1.w;
        __half2 p0 = __float22half2_rn(make_float2(o0, o1));
        __half2 p1 = __float22half2_rn(make_float2(o2, o3));
        __half2 p2 = __float22half2_rn(make_float2(o4, o5));
        __half2 p3 = __float22half2_rn(make_float2(o6, o7));
        uint4 st;
        st.x = __builtin_bit_cast(unsigned int, p0);
        st.y = __builtin_bit_cast(unsigned int, p1);
        st.z = __builtin_bit_cast(unsigned int, p2);
        st.w = __builtin_bit_cast(unsigned int, p3);
        ((uint4*)(h1p + (size_t)i * NHID + s * 32))[fl] = st;  // standard layout for gemm2
    }
}

// ---------------- agg2 + bias + log_softmax: plane0 (cls 0..31) + plane1 (cls 32..39) ----------------
__global__ __launch_bounds__(256, 8) void k_agg2(const __half* __restrict__ h2p,
                                                 const float* __restrict__ dinv,
                                                 const int* __restrict__ row_beg,
                                                 const int* __restrict__ row_cnt,
                                                 const int* __restrict__ esrc,
                                                 const float* __restrict__ b2,
                                                 float* __restrict__ out) {
    int i = blockIdx.x * 4 + (threadIdx.x >> 6);
    int lane = threadIdx.x & 63;
    int g = lane >> 2;
    int fl = lane & 3;
    const uint4* hp0 = (const uint4*)h2p;
    const uint4* hp1 = (const uint4*)(h2p + PL2A);
    float di = dinv[i];
    __half2 a0[4], a1[4];
    __half2 hz = __half2half2(__float2half(0.0f));
    #pragma unroll
    for (int r = 0; r < 4; r++) { a0[r] = hz; a1[r] = hz; }
    int s0 = row_beg[i], cnt = row_cnt[i];
    for (int base = 0; base < cnt; base += 64) {
        int idx = base + lane;
        int sv = (idx < cnt) ? esrc[s0 + idx] : 0;
        float dv = (idx < cnt) ? dinv[sv] : 0.0f;
        // plane1: one edge per lane, full 16B row
        uint4 v1 = hp1[sv];
        __half2 dvh = __half2half2(__float2half(dv));
        a1[0] = __hfma2(__builtin_bit_cast(__half2, v1.x), dvh, a1[0]);
        a1[1] = __hfma2(__builtin_bit_cast(__half2, v1.y), dvh, a1[1]);
        a1[2] = __hfma2(__builtin_bit_cast(__half2, v1.z), dvh, a1[2]);
        a1[3] = __hfma2(__builtin_bit_cast(__half2, v1.w), dvh, a1[3]);
        // plane0: 4-lane groups, 64B rows
        int ss[4]; __half2 dd[4]; uint4 vv[4];
        #pragma unroll
        for (int k = 0; k < 4; k++) {
            int jx = k * 16 + g;
            ss[k] = __shfl(sv, jx);
            dd[k] = __half2half2(__float2half(__shfl(dv, jx)));
        }
        #pragma unroll
        for (int k = 0; k < 4; k++) vv[k] = hp0[(size_t)ss[k] * 4 + fl];
        #pragma unroll
        for (int k = 0; k < 4; k++) {
            a0[0] = __hfma2(__builtin_bit_cast(__half2, vv[k].x), dd[k], a0[0]);
            a0[1] = __hfma2(__builtin_bit_cast(__half2, vv[k].y), dd[k], a0[1]);
            a0[2] = __hfma2(__builtin_bit_cast(__half2, vv[k].z), dd[k], a0[2]);
            a0[3] = __hfma2(__builtin_bit_cast(__half2, vv[k].w), dd[k], a0[3]);
        }
    }
    // a1: full-wave reduce (strides 1..32); a0: group reduce (strides 4..32)
    #pragma unroll
    for (int d = 1; d <= 32; d <<= 1) {
        #pragma unroll
        for (int r = 0; r < 4; r++) {
            unsigned int u = __shfl_xor(__builtin_bit_cast(unsigned int, a1[r]), d);
            a1[r] = __hadd2(a1[r], __builtin_bit_cast(__half2, u));
            if (d >= 4) {
                unsigned int u0 = __shfl_xor(__builtin_bit_cast(unsigned int, a0[r]), d);
                a0[r] = __hadd2(a0[r], __builtin_bit_cast(__half2, u0));
            }
        }
    }
    float val0[8], val1[8];
    if (g == 0) {   // lanes 0..3: classes [fl*8, fl*8+8)
        float acc[8];
        #pragma unroll
        for (int r = 0; r < 4; r++) {
            float2 f = __half22float2(a0[r]);
            acc[2 * r] = f.x; acc[2 * r + 1] = f.y;
        }
        uint4 s4 = hp0[(size_t)i * 4 + fl];
        acc8f(acc, s4, di);
        float4 bb0 = *(const float4*)(b2 + fl * 8);
        float4 bb1 = *(const float4*)(b2 + fl * 8 + 4);
        val0[0] = fmaf(acc[0], di, bb0.x);
        val0[1] = fmaf(acc[1], di, bb0.y);
        val0[2] = fmaf(acc[2], di, bb0.z);
        val0[3] = fmaf(acc[3], di, bb0.w);
        val0[4] = fmaf(acc[4], di, bb1.x);
        val0[5] = fmaf(acc[5], di, bb1.y);
        val0[6] = fmaf(acc[6], di, bb1.z);
        val0[7] = fmaf(acc[7], di, bb1.w);
    }
    if (lane == 0) {  // classes 32..39
        float acc[8];
        #pragma unroll
        for (int r = 0; r < 4; r++) {
            float2 f = __half22float2(a1[r]);
            acc[2 * r] = f.x; acc[2 * r + 1] = f.y;
        }
        acc8f(acc, hp1[i], di);   // self term
        float4 bb0 = *(const float4*)(b2 + 32);
        float4 bb1 = *(const float4*)(b2 + 36);
        val1[0] = fmaf(acc[0], di, bb0.x);
        val1[1] = fmaf(acc[1], di, bb0.y);
        val1[2] = fmaf(acc[2], di, bb0.z);
        val1[3] = fmaf(acc[3], di, bb0.w);
        val1[4] = fmaf(acc[4], di, bb1.x);
        val1[5] = fmaf(acc[5], di, bb1.y);
        val1[6] = fmaf(acc[6], di, bb1.z);
        val1[7] = fmaf(acc[7], di, bb1.w);
    }
    // softmax over 40 classes spread across lanes 0..3 (+8 extra on lane 0)
    float m = -INFINITY;
    if (g == 0) {
        #pragma unroll
        for (int k = 0; k < 8; k++) m = fmaxf(m, val0[k]);
    }
    if (lane == 0) {
        #pragma unroll
        for (int k = 0; k < 8; k++) m = fmaxf(m, val1[k]);
    }
    m = fmaxf(m, __shfl_xor(m, 1));
    m = fmaxf(m, __shfl_xor(m, 2));
    float ssum = 0.f;
    if (g == 0) {
        #pragma unroll
        for (int k = 0; k < 8; k++) ssum += expf(val0[k] - m);
    }
    if (lane == 0) {
        #pragma unroll
        for (int k = 0; k < 8; k++) ssum += expf(val1[k] - m);
    }
    ssum += __shfl_xor(ssum, 1);
    ssum += __shfl_xor(ssum, 2);
    if (g == 0) {
        float ls = m + logf(ssum);
        float4 r0 = make_float4(val0[0] - ls, val0[1] - ls, val0[2] - ls, val0[3] - ls);
        float4 r1 = make_float4(val0[4] - ls, val0[5] - ls, val0[6] - ls, val0[7] - ls);
        float4* orow = (float4*)(out + (size_t)i * NCLASS + fl * 8);
        orow[0] = r0;
        orow[1] = r1;
        if (lane == 0) {
            float4 r2 = make_float4(val1[0] - ls, val1[1] - ls, val1[2] - ls, val1[3] - ls);
            float4 r3 = make_float4(val1[4] - ls, val1[5] - ls, val1[6] - ls, val1[7] - ls);
            float4* orow1 = (float4*)(out + (size_t)i * NCLASS + 32);
            orow1[0] = r2;
            orow1[1] = r3;
        }
    }
}

extern "C" void kernel_launch(void* const* d_in, const int* in_sizes, int n_in,
                              void* d_out, int out_size, void* d_ws, size_t ws_size,
                              hipStream_t stream) {
    const float* x    = (const float*)d_in[0];
    const int*   ei   = (const int*)d_in[1];
    const float* W1   = (const float*)d_in[2];
    const float* b1   = (const float*)d_in[3];
    const float* W2   = (const float*)d_in[4];
    const float* b2   = (const float*)d_in[5];
    const float* mask = (const float*)d_in[6];
    float* out = (float*)d_out;

    const int* src = ei;
    const int* dst = ei + N_EDGES;

    char* ws = (char*)d_ws;
    size_t off = 0;
    __half* h1p    = (__half*)(ws + off); off += (size_t)N_NODES * NHID * 2;   // 12.8 MB
    __half* h1h    = (__half*)(ws + off); off += (size_t)N_NODES * NHID * 2;   // 12.8 MB
    int*    esrc   = (int*)   (ws + off); off += (size_t)NBUCK * CAP * 4;      // 8.0 MB
    float*  dinv   = (float*) (ws + off); off += 200192;
    int*   row_beg = (int*)   (ws + off); off += 200192;
    int*   row_cnt = (int*)   (ws + off); off += 200192;
    int*   gcur    = (int*)   (ws + off); off += 2048;
    __half* w1t    = (__half*)(ws + off); off += 128 * 256 * 2;                // 64 KB
    __half* w2t    = (__half*)(ws + off); off += 48 * 128 * 2;                 // 12 KB

    unsigned int* packed = (unsigned int*)h1p;  // binA/binB lifetime only
    __half* h2p = h1h;                           // gemm2/agg2 lifetime only (4.0 MB used)

    k_prep<<<128, 256, 0, stream>>>(W1, W2, w1t, w2t, gcur);
    k_binA<<<(N_EDGES + EPB - 1) / EPB, 256, 0, stream>>>(src, dst, gcur, packed);
    k_binB<<<NBUCK, 256, 0, stream>>>(gcur, packed, esrc, row_beg, row_cnt, dinv);

    k_gemm1<<<(N_NODES + 63) / 64, 256, 0, stream>>>(x, w1t, h1h);
    k_agg1<<<50000, 256, 0, stream>>>(h1h, dinv, row_beg, row_cnt, esrc, b1, mask, h1p);
    k_gemm2<<<(N_NODES + 63) / 64, 256, 0, stream>>>(h1p, w2t, h2p);
    k_agg2<<<12500, 256, 0, stream>>>(h2p, dinv, row_beg, row_cnt, esrc, b2, out);
}

// Round 4
// 278.936 us; speedup vs baseline: 1.1936x; 1.1936x over previous
//
#include <hip/hip_runtime.h>
#include <hip/hip_fp16.h>
#include <math.h>

#define N_NODES 50000
#define N_EDGES 1600000
#define NFEAT 256
#define NHID 128
#define NCLASS 40

#define NPAD 50048           // grid-rounded node count (dummy zero rows live at >= N_NODES)
#define DUMMY N_NODES        // index of a guaranteed-zero table row

#define BSHIFT 7
#define NBUCK 391            // ceil(50000 / 128)
#define CAP 5120             // per-bucket capacity (mean 4092)
#define EPB 4096             // edges per binA block -> 391 blocks

typedef _Float16 f16x8 __attribute__((ext_vector_type(8)));
typedef float f32x4 __attribute__((ext_vector_type(4)));

// ---------------- pass A: coarse binning by dst>>7 ----------------
__global__ __launch_bounds__(256) void k_binA(const int* __restrict__ src,
                                              const int* __restrict__ dst,
                                              int* __restrict__ gcur,
                                              unsigned int* __restrict__ packed) {
    __shared__ int lhist[NBUCK];
    __shared__ int lbase[NBUCK];
    __shared__ int lcur[NBUCK];
    int t = threadIdx.x;
    for (int i = t; i < NBUCK; i += 256) { lhist[i] = 0; lcur[i] = 0; }
    __syncthreads();
    int e0 = blockIdx.x * EPB;
    int e1 = min(e0 + EPB, N_EDGES);
    for (int e = e0 + t; e < e1; e += 256) {
        int b = dst[e] >> BSHIFT;
        atomicAdd(&lhist[b], 1);
    }
    __syncthreads();
    for (int i = t; i < NBUCK; i += 256)
        lbase[i] = atomicAdd(&gcur[i], lhist[i]);
    __syncthreads();
    for (int e = e0 + t; e < e1; e += 256) {
        int d = dst[e];
        int b = d >> BSHIFT;
        int r = atomicAdd(&lcur[b], 1);
        int pos = lbase[b] + r;
        if (pos < CAP)
            packed[(size_t)b * CAP + pos] =
                ((unsigned int)src[e] << BSHIFT) | (unsigned int)(d & 127);
    }
}

// ---------------- pass B: in-LDS fine sort per bucket + CSR metadata ----------------
__global__ __launch_bounds__(256) void k_binB(const int* __restrict__ gcur,
                                              const unsigned int* __restrict__ packed,
                                              int* __restrict__ esrc,
                                              int* __restrict__ row_beg,
                                              int* __restrict__ row_cnt,
                                              float* __restrict__ dinv) {
    __shared__ unsigned int sp[CAP];     // 20 KB
    __shared__ int hist[128];
    __shared__ int scan[128];
    __shared__ int cur[128];
    int b = blockIdx.x;
    int t = threadIdx.x;
    int cnt = min(gcur[b], CAP);
    if (t < 128) { hist[t] = 0; cur[t] = 0; }
    __syncthreads();
    const unsigned int* pin = packed + (size_t)b * CAP;
    for (int i = t; i < cnt; i += 256) {
        unsigned int w = pin[i];
        sp[i] = w;
        atomicAdd(&hist[w & 127], 1);
    }
    __syncthreads();
    if (t == 0) {
        int s = 0;
        for (int i = 0; i < 128; i++) { scan[i] = s; s += hist[i]; }
    }
    __syncthreads();
    for (int i = t; i < cnt; i += 256) {
        unsigned int w = sp[i];
        int dl = (int)(w & 127u);
        int r = atomicAdd(&cur[dl], 1);
        esrc[(size_t)b * CAP + scan[dl] + r] = (int)(w >> BSHIFT);
    }
    if (t < 128) {
        int node = b * 128 + t;
        if (node < N_NODES) {
            row_beg[node] = b * CAP + scan[t];
            row_cnt[node] = hist[t];
            dinv[node] = rsqrtf((float)(hist[t] + 1));
        }
    }
}

// ---------------- prep: W transposes to fp16 + gcur zero + dinv tail zero ----------------
__global__ __launch_bounds__(256) void k_prep(const float* __restrict__ W1,
                                              const float* __restrict__ W2,
                                              __half* __restrict__ w1t,
                                              __half* __restrict__ w2t,
                                              int* __restrict__ gcur,
                                              float* __restrict__ dinv) {
    int t = blockIdx.x * 256 + threadIdx.x;
    if (t < NBUCK) gcur[t] = 0;
    if (t < 128 * 256) {
        int n = t >> 8, k = t & 255;
        w1t[t] = __float2half(W1[k * NHID + n]);
    }
    if (t < 48 * 128) {
        int n = t >> 7, k = t & 127;
        w2t[t] = __float2half(n < NCLASS ? W2[k * NCLASS + n] : 0.0f);
    }
    if (t >= N_NODES && t < NPAD) dinv[t] = 0.0f;   // dummy rows scale to zero
}

// ---------------- GEMM1 (MFMA): h1h(fp16) = (x @ W1) * dinv[row]  (pre-scaled table) ----------------
#define G1_LDA 72
#define G1_LDB 72
#define G1_LDE 136
__global__ __launch_bounds__(256) void k_gemm1(const float* __restrict__ x,
                                               const __half* __restrict__ w1t,
                                               const float* __restrict__ dinv,
                                               __half* __restrict__ h1h) {
    __shared__ __half smem[64 * G1_LDA + 128 * G1_LDB];   // 27.6 KB
    __half* sA = smem;
    __half* sB = smem + 64 * G1_LDA;
    int t = threadIdx.x;
    int rbase = blockIdx.x * 64;
    int lane = t & 63, wv = t >> 6;
    int m = lane & 15, quad = lane >> 4;
    f32x4 acc[8];
    #pragma unroll
    for (int i = 0; i < 8; i++) acc[i] = (f32x4)0.0f;

    int arow = t >> 2, aseg = t & 3;
    int grow = rbase + arow;
    bool avalid = grow < N_NODES;
    int bn = t >> 1, bseg = t & 1;

    for (int k0 = 0; k0 < NFEAT; k0 += 64) {
        const float4* gs = (const float4*)(x + (size_t)grow * NFEAT + k0 + aseg * 16);
        __half* ad = sA + arow * G1_LDA + aseg * 16;
        #pragma unroll
        for (int i = 0; i < 4; i++) {
            float4 v = avalid ? gs[i] : make_float4(0.f, 0.f, 0.f, 0.f);
            __half2 h0 = __float22half2_rn(make_float2(v.x, v.y));
            __half2 h1 = __float22half2_rn(make_float2(v.z, v.w));
            uint2 st;
            st.x = __builtin_bit_cast(unsigned int, h0);
            st.y = __builtin_bit_cast(unsigned int, h1);
            *(uint2*)(ad + i * 4) = st;
        }
        const uint4* ws4 = (const uint4*)(w1t + bn * NFEAT + k0 + bseg * 32);
        uint4* bd = (uint4*)(sB + bn * G1_LDB + bseg * 32);
        #pragma unroll
        for (int i = 0; i < 4; i++) bd[i] = ws4[i];
        __syncthreads();
        #pragma unroll
        for (int kk = 0; kk < 64; kk += 32) {
            f16x8 af = *(const f16x8*)(sA + (wv * 16 + m) * G1_LDA + kk + quad * 8);
            #pragma unroll
            for (int t8 = 0; t8 < 8; t8++) {
                f16x8 bf = *(const f16x8*)(sB + (t8 * 16 + m) * G1_LDB + kk + quad * 8);
                acc[t8] = __builtin_amdgcn_mfma_f32_16x16x32_f16(af, bf, acc[t8], 0, 0, 0);
            }
        }
        __syncthreads();
    }
    // pre-scale each output row by dinv[row] while packing (rows >= N_NODES have dinv=0 -> zero rows)
    float di4[4];
    #pragma unroll
    for (int r = 0; r < 4; r++) di4[r] = dinv[rbase + wv * 16 + quad * 4 + r];
    __half* eb = smem;
    #pragma unroll
    for (int t8 = 0; t8 < 8; t8++) {
        #pragma unroll
        for (int r = 0; r < 4; r++)
            eb[(wv * 16 + quad * 4 + r) * G1_LDE + t8 * 16 + m] = __float2half(acc[t8][r] * di4[r]);
    }
    __syncthreads();
    {   // unconditional store: grid covers exactly NPAD rows; dummy rows are zeros
        const uint4* es = (const uint4*)(eb + arow * G1_LDE + aseg * 32);
        uint4* od = (uint4*)(h1h + (size_t)grow * NHID + aseg * 32);
        #pragma unroll
        for (int i = 0; i < 4; i++) od[i] = es[i];
    }
}

// ---------------- GEMM2 (MFMA): h2p(fp16, stride 64) = (h1p @ W2) * dinv[row] ----------------
#define G2_LDA 136
#define G2_LDB 136
#define G2_LDE 72
__global__ __launch_bounds__(256) void k_gemm2(const __half* __restrict__ h1p,
                                               const __half* __restrict__ w2t,
                                               const float* __restrict__ dinv,
                                               __half* __restrict__ h2p) {
    __shared__ __half smem[64 * G2_LDA + 48 * G2_LDB];  // 30.5 KB
    __half* sA = smem;
    __half* sB = smem + 64 * G2_LDA;
    int t = threadIdx.x;
    int rbase = blockIdx.x * 64;
    int lane = t & 63, wv = t >> 6;
    int m = lane & 15, quad = lane >> 4;
    f32x4 acc[3];
    #pragma unroll
    for (int i = 0; i < 3; i++) acc[i] = (f32x4)0.0f;

    int arow = t >> 2, aseg = t & 3;
    int grow = rbase + arow;
    bool avalid = grow < N_NODES;

    #pragma unroll
    for (int i = 0; i < 3; i++) {
        int idx = t + i * 256;
        int n = idx >> 4, seg = idx & 15;
        *(uint4*)(sB + n * G2_LDB + seg * 8) = *(const uint4*)(w2t + n * NHID + seg * 8);
    }
    {
        const uint4* gs = (const uint4*)(h1p + (size_t)grow * NHID + aseg * 32);
        uint4* ad = (uint4*)(sA + arow * G2_LDA + aseg * 32);
        uint4 z; z.x = z.y = z.z = z.w = 0;
        #pragma unroll
        for (int i = 0; i < 4; i++) ad[i] = avalid ? gs[i] : z;
    }
    __syncthreads();
    #pragma unroll
    for (int kk = 0; kk < 128; kk += 32) {
        f16x8 af = *(const f16x8*)(sA + (wv * 16 + m) * G2_LDA + kk + quad * 8);
        #pragma unroll
        for (int t3 = 0; t3 < 3; t3++) {
            f16x8 bf = *(const f16x8*)(sB + (t3 * 16 + m) * G2_LDB + kk + quad * 8);
            acc[t3] = __builtin_amdgcn_mfma_f32_16x16x32_f16(af, bf, acc[t3], 0, 0, 0);
        }
    }
    __syncthreads();
    float di4[4];
    #pragma unroll
    for (int r = 0; r < 4; r++) di4[r] = dinv[rbase + wv * 16 + quad * 4 + r];
    __half* eb = smem;
    #pragma unroll
    for (int t3 = 0; t3 < 3; t3++) {
        #pragma unroll
        for (int r = 0; r < 4; r++)
            eb[(wv * 16 + quad * 4 + r) * G2_LDE + t3 * 16 + m] = __float2half(acc[t3][r] * di4[r]);
    }
    {
        int zr = t >> 2, zc = 48 + (t & 3) * 4;
        uint2 z; z.x = z.y = 0;
        *(uint2*)(eb + zr * G2_LDE + zc) = z;
    }
    __syncthreads();
    #pragma unroll
    for (int i = 0; i < 2; i++) {
        int idx = t + i * 256;
        int row = idx >> 3, seg = idx & 7;
        int gr = rbase + row;   // unconditional: dummy rows store zeros (acc*0)
        *(uint4*)(h2p + (size_t)gr * 64 + seg * 8) = *(const uint4*)(eb + row * G2_LDE + seg * 8);
    }
}

__device__ __forceinline__ void acc8f(float* acc, uint4 v, float d) {
    float2 a0 = __half22float2(__builtin_bit_cast(__half2, v.x));
    float2 a1 = __half22float2(__builtin_bit_cast(__half2, v.y));
    float2 a2 = __half22float2(__builtin_bit_cast(__half2, v.z));
    float2 a3 = __half22float2(__builtin_bit_cast(__half2, v.w));
    acc[0] = fmaf(a0.x, d, acc[0]); acc[1] = fmaf(a0.y, d, acc[1]);
    acc[2] = fmaf(a1.x, d, acc[2]); acc[3] = fmaf(a1.y, d, acc[3]);
    acc[4] = fmaf(a2.x, d, acc[4]); acc[5] = fmaf(a2.y, d, acc[5]);
    acc[6] = fmaf(a3.x, d, acc[6]); acc[7] = fmaf(a3.y, d, acc[7]);
}

// ---------------- agg1: shuffle-free, dinv-free (pre-scaled table), 8-deep gathers ----------------
// 4 waves/block, 1 node/wave. 16-lane groups own one 16B chunk; 4 groups process 4 edges/step.
__global__ __launch_bounds__(256, 8) void k_agg1(const __half* __restrict__ h1h,
                                                 const float* __restrict__ dinv,
                                                 const int* __restrict__ row_beg,
                                                 const int* __restrict__ row_cnt,
                                                 const int* __restrict__ esrc,
                                                 const float* __restrict__ b1,
                                                 const float* __restrict__ mask,
                                                 __half* __restrict__ h1p) {
    int i = blockIdx.x * 4 + (threadIdx.x >> 6);   // N_NODES = 4*12500 exactly
    int lane = threadIdx.x & 63;
    int g = lane >> 4;          // edge group 0..3
    int fl = lane & 15;         // 16B chunk of the 256B row
    const uint4* hv4 = (const uint4*)h1h;
    float di = dinv[i];
    __half2 hacc[4];
    __half2 hz = __half2half2(__float2half(0.0f));
    hacc[0] = hz; hacc[1] = hz; hacc[2] = hz; hacc[3] = hz;
    int s0 = row_beg[i], cnt = row_cnt[i];
    unsigned cm1 = (unsigned)(cnt - 1);
    for (int base = 0; base < cnt; base += 64) {
        #pragma unroll
        for (int h = 0; h < 2; h++) {
            int e8[8]; uint4 vv[8];
            #pragma unroll
            for (int k = 0; k < 8; k++) {
                int jx = base + (h * 8 + k) * 4 + g;
                unsigned li = min((unsigned)jx, cm1);
                int e = esrc[s0 + (int)li];
                e8[k] = (jx < cnt) ? e : DUMMY;     // dummy -> zero row
            }
            #pragma unroll
            for (int k = 0; k < 8; k++) vv[k] = hv4[(size_t)e8[k] * 16 + fl];
            #pragma unroll
            for (int k = 0; k < 8; k++) {
                hacc[0] = __hadd2(hacc[0], __builtin_bit_cast(__half2, vv[k].x));
                hacc[1] = __hadd2(hacc[1], __builtin_bit_cast(__half2, vv[k].y));
                hacc[2] = __hadd2(hacc[2], __builtin_bit_cast(__half2, vv[k].z));
                hacc[3] = __hadd2(hacc[3], __builtin_bit_cast(__half2, vv[k].w));
            }
        }
    }
    // reduce across the 4 edge groups (strides 16, 32)
    #pragma unroll
    for (int d = 16; d <= 32; d <<= 1) {
        #pragma unroll
        for (int r = 0; r < 4; r++) {
            unsigned int u = __shfl_xor(__builtin_bit_cast(unsigned int, hacc[r]), d);
            hacc[r] = __hadd2(hacc[r], __builtin_bit_cast(__half2, u));
        }
    }
    if (g == 0) {
        float acc[8];
        #pragma unroll
        for (int r = 0; r < 4; r++) {
            float2 f = __half22float2(hacc[r]);
            acc[2 * r] = f.x; acc[2 * r + 1] = f.y;
        }
        uint4 sv4 = hv4[(size_t)i * 16 + fl];      // self row (already *dinv[i])
        acc8f(acc, sv4, 1.0f);
        float4 bb0 = ((const float4*)b1)[fl * 2];
        float4 bb1 = ((const float4*)b1)[fl * 2 + 1];
        const float4* mrow = (const float4*)(mask + (size_t)i * NHID);
        float4 mm0 = mrow[fl * 2];
        float4 mm1 = mrow[fl * 2 + 1];
        float o0 = fmaxf(fmaf(acc[0], di, bb0.x), 0.f) * mm0.x;
        float o1 = fmaxf(fmaf(acc[1], di, bb0.y), 0.f) * mm0.y;
        float o2 = fmaxf(fmaf(acc[2], di, bb0.z), 0.f) * mm0.z;
        float o3 = fmaxf(fmaf(acc[3], di, bb0.w), 0.f) * mm0.w;
        float o4 = fmaxf(fmaf(acc[4], di, bb1.x), 0.f) * mm1.x;
        float o5 = fmaxf(fmaf(acc[5], di, bb1.y), 0.f) * mm1.y;
        float o6 = fmaxf(fmaf(acc[6], di, bb1.z), 0.f) * mm1.z;
        float o7 = fmaxf(fmaf(acc[7], di, bb1.w), 0.f) * mm1.w;
        __half2 p0 = __float22half2_rn(make_float2(o0, o1));
        __half2 p1 = __float22half2_rn(make_float2(o2, o3));
        __half2 p2 = __float22half2_rn(make_float2(o4, o5));
        __half2 p3 = __float22half2_rn(make_float2(o6, o7));
        uint4 st;
        st.x = __builtin_bit_cast(unsigned int, p0);
        st.y = __builtin_bit_cast(unsigned int, p1);
        st.z = __builtin_bit_cast(unsigned int, p2);
        st.w = __builtin_bit_cast(unsigned int, p3);
        ((uint4*)h1p)[(size_t)i * 16 + fl] = st;
    }
}

// ---------------- agg2 + bias + log_softmax: shuffle-free, dinv-free ----------------
// 8-lane groups own one 16B chunk of the 128B row; 8 groups process 8 edges/step.
__global__ __launch_bounds__(256, 8) void k_agg2(const __half* __restrict__ h2p,
                                                 const float* __restrict__ dinv,
                                                 const int* __restrict__ row_beg,
                                                 const int* __restrict__ row_cnt,
                                                 const int* __restrict__ esrc,
                                                 const float* __restrict__ b2,
                                                 float* __restrict__ out) {
    int i = blockIdx.x * 4 + (threadIdx.x >> 6);
    int lane = threadIdx.x & 63;
    int g = lane >> 3;          // edge group 0..7
    int fl = lane & 7;          // 16B chunk of the 128B row
    const uint4* hv4 = (const uint4*)h2p;
    float di = dinv[i];
    __half2 hacc[4];
    __half2 hz = __half2half2(__float2half(0.0f));
    hacc[0] = hz; hacc[1] = hz; hacc[2] = hz; hacc[3] = hz;
    int s0 = row_beg[i], cnt = row_cnt[i];
    unsigned cm1 = (unsigned)(cnt - 1);
    for (int base = 0; base < cnt; base += 64) {
        int e8[8]; uint4 vv[8];
        #pragma unroll
        for (int k = 0; k < 8; k++) {
            int jx = base + k * 8 + g;
            unsigned li = min((unsigned)jx, cm1);
            int e = esrc[s0 + (int)li];
            e8[k] = (jx < cnt) ? e : DUMMY;
        }
        #pragma unroll
        for (int k = 0; k < 8; k++) vv[k] = hv4[(size_t)e8[k] * 8 + fl];
        #pragma unroll
        for (int k = 0; k < 8; k++) {
            hacc[0] = __hadd2(hacc[0], __builtin_bit_cast(__half2, vv[k].x));
            hacc[1] = __hadd2(hacc[1], __builtin_bit_cast(__half2, vv[k].y));
            hacc[2] = __hadd2(hacc[2], __builtin_bit_cast(__half2, vv[k].z));
            hacc[3] = __hadd2(hacc[3], __builtin_bit_cast(__half2, vv[k].w));
        }
    }
    // reduce across the 8 edge groups (strides 8, 16, 32)
    #pragma unroll
    for (int d = 8; d <= 32; d <<= 1) {
        #pragma unroll
        for (int r = 0; r < 4; r++) {
            unsigned int u = __shfl_xor(__builtin_bit_cast(unsigned int, hacc[r]), d);
            hacc[r] = __hadd2(hacc[r], __builtin_bit_cast(__half2, u));
        }
    }
    if (g == 0) {
        bool act = (fl < 5);
        float acc[8];
        #pragma unroll
        for (int r = 0; r < 4; r++) {
            float2 f = __half22float2(hacc[r]);
            acc[2 * r] = f.x; acc[2 * r + 1] = f.y;
        }
        uint4 sv4 = hv4[(size_t)i * 8 + fl];
        acc8f(acc, sv4, 1.0f);
        float val[8];
        float m = -INFINITY;
        if (act) {
            float4 bb0 = ((const float4*)b2)[fl * 2];
            float4 bb1 = ((const float4*)b2)[fl * 2 + 1];
            val[0] = fmaf(acc[0], di, bb0.x);
            val[1] = fmaf(acc[1], di, bb0.y);
            val[2] = fmaf(acc[2], di, bb0.z);
            val[3] = fmaf(acc[3], di, bb0.w);
            val[4] = fmaf(acc[4], di, bb1.x);
            val[5] = fmaf(acc[5], di, bb1.y);
            val[6] = fmaf(acc[6], di, bb1.z);
            val[7] = fmaf(acc[7], di, bb1.w);
            #pragma unroll
            for (int k = 0; k < 8; k++) m = fmaxf(m, val[k]);
        }
        m = fmaxf(m, __shfl_xor(m, 1));
        m = fmaxf(m, __shfl_xor(m, 2));
        m = fmaxf(m, __shfl_xor(m, 4));
        float ss = 0.f;
        if (act) {
            #pragma unroll
            for (int k = 0; k < 8; k++) ss += expf(val[k] - m);
        }
        ss += __shfl_xor(ss, 1);
        ss += __shfl_xor(ss, 2);
        ss += __shfl_xor(ss, 4);
        if (act) {
            float ls = m + logf(ss);
            float4 r0 = make_float4(val[0] - ls, val[1] - ls, val[2] - ls, val[3] - ls);
            float4 r1 = make_float4(val[4] - ls, val[5] - ls, val[6] - ls, val[7] - ls);
            float4* orow = (float4*)(out + (size_t)i * NCLASS + fl * 8);
            orow[0] = r0;
            orow[1] = r1;
        }
    }
}

extern "C" void kernel_launch(void* const* d_in, const int* in_sizes, int n_in,
                              void* d_out, int out_size, void* d_ws, size_t ws_size,
                              hipStream_t stream) {
    const float* x    = (const float*)d_in[0];
    const int*   ei   = (const int*)d_in[1];
    const float* W1   = (const float*)d_in[2];
    const float* b1   = (const float*)d_in[3];
    const float* W2   = (const float*)d_in[4];
    const float* b2   = (const float*)d_in[5];
    const float* mask = (const float*)d_in[6];
    float* out = (float*)d_out;

    const int* src = ei;
    const int* dst = ei + N_EDGES;

    char* ws = (char*)d_ws;
    size_t off = 0;
    __half* h1p    = (__half*)(ws + off); off += (size_t)NPAD * NHID * 2;      // 12.8 MB (incl. dummy rows)
    __half* h1h    = (__half*)(ws + off); off += (size_t)NPAD * NHID * 2;      // 12.8 MB
    int*    esrc   = (int*)   (ws + off); off += (size_t)NBUCK * CAP * 4 + 256;// 8.0 MB (+tail pad)
    float*  dinv   = (float*) (ws + off); off += 200192;
    int*   row_beg = (int*)   (ws + off); off += 200192;
    int*   row_cnt = (int*)   (ws + off); off += 200192;
    int*   gcur    = (int*)   (ws + off); off += 2048;
    __half* w1t    = (__half*)(ws + off); off += 128 * 256 * 2;                // 64 KB
    __half* w2t    = (__half*)(ws + off); off += 48 * 128 * 2;                 // 12 KB

    unsigned int* packed = (unsigned int*)h1p;  // binA/binB lifetime only
    __half* h2p = h1h;                           // gemm2/agg2 lifetime only (6.4 MB used)

    k_prep<<<196, 256, 0, stream>>>(W1, W2, w1t, w2t, gcur, dinv);
    k_binA<<<(N_EDGES + EPB - 1) / EPB, 256, 0, stream>>>(src, dst, gcur, packed);
    k_binB<<<NBUCK, 256, 0, stream>>>(gcur, packed, esrc, row_beg, row_cnt, dinv);

    k_gemm1<<<NPAD / 64, 256, 0, stream>>>(x, w1t, dinv, h1h);
    k_agg1<<<N_NODES / 4, 256, 0, stream>>>(h1h, dinv, row_beg, row_cnt, esrc, b1, mask, h1p);
    k_gemm2<<<NPAD / 64, 256, 0, stream>>>(h1p, w2t, dinv, h2p);
    k_agg2<<<N_NODES / 4, 256, 0, stream>>>(h2p, dinv, row_beg, row_cnt, esrc, b2, out);
}

// Round 5
// 264.746 us; speedup vs baseline: 1.2576x; 1.0536x over previous
//
#include <hip/hip_runtime.h>
#include <hip/hip_fp16.h>
#include <math.h>

#define N_NODES 50000
#define N_EDGES 1600000
#define NFEAT 256
#define NHID 128
#define NCLASS 40

#define NPAD 50048           // grid-rounded node count (dummy zero rows live at >= N_NODES)
#define DUMMY N_NODES        // index of a guaranteed-zero table row

#define BSHIFT 7
#define NBUCK 391            // ceil(50000 / 128)
#define CAP 5120             // per-bucket capacity (mean 4092)
#define EPB 4096             // edges per binA block -> 391 blocks

typedef _Float16 f16x8 __attribute__((ext_vector_type(8)));
typedef float f32x4 __attribute__((ext_vector_type(4)));

// ---------------- pass A: coarse binning by dst>>7 ----------------
__global__ __launch_bounds__(256) void k_binA(const int* __restrict__ src,
                                              const int* __restrict__ dst,
                                              int* __restrict__ gcur,
                                              unsigned int* __restrict__ packed) {
    __shared__ int lhist[NBUCK];
    __shared__ int lbase[NBUCK];
    __shared__ int lcur[NBUCK];
    int t = threadIdx.x;
    for (int i = t; i < NBUCK; i += 256) { lhist[i] = 0; lcur[i] = 0; }
    __syncthreads();
    int e0 = blockIdx.x * EPB;
    int e1 = min(e0 + EPB, N_EDGES);
    for (int e = e0 + t; e < e1; e += 256) {
        int b = dst[e] >> BSHIFT;
        atomicAdd(&lhist[b], 1);
    }
    __syncthreads();
    for (int i = t; i < NBUCK; i += 256)
        lbase[i] = atomicAdd(&gcur[i], lhist[i]);
    __syncthreads();
    for (int e = e0 + t; e < e1; e += 256) {
        int d = dst[e];
        int b = d >> BSHIFT;
        int r = atomicAdd(&lcur[b], 1);
        int pos = lbase[b] + r;
        if (pos < CAP)
            packed[(size_t)b * CAP + pos] =
                ((unsigned int)src[e] << BSHIFT) | (unsigned int)(d & 127);
    }
}

// ---------------- pass B: in-LDS fine sort per bucket + CSR metadata ----------------
__global__ __launch_bounds__(256) void k_binB(const int* __restrict__ gcur,
                                              const unsigned int* __restrict__ packed,
                                              int* __restrict__ esrc,
                                              int* __restrict__ row_beg,
                                              int* __restrict__ row_cnt,
                                              float* __restrict__ dinv) {
    __shared__ unsigned int sp[CAP];     // 20 KB
    __shared__ int hist[128];
    __shared__ int scan[128];
    __shared__ int cur[128];
    int b = blockIdx.x;
    int t = threadIdx.x;
    int cnt = min(gcur[b], CAP);
    if (t < 128) { hist[t] = 0; cur[t] = 0; }
    __syncthreads();
    const unsigned int* pin = packed + (size_t)b * CAP;
    for (int i = t; i < cnt; i += 256) {
        unsigned int w = pin[i];
        sp[i] = w;
        atomicAdd(&hist[w & 127], 1);
    }
    __syncthreads();
    if (t == 0) {
        int s = 0;
        for (int i = 0; i < 128; i++) { scan[i] = s; s += hist[i]; }
    }
    __syncthreads();
    for (int i = t; i < cnt; i += 256) {
        unsigned int w = sp[i];
        int dl = (int)(w & 127u);
        int r = atomicAdd(&cur[dl], 1);
        esrc[(size_t)b * CAP + scan[dl] + r] = (int)(w >> BSHIFT);
    }
    if (t < 128) {
        int node = b * 128 + t;
        if (node < N_NODES) {
            row_beg[node] = b * CAP + scan[t];
            row_cnt[node] = hist[t];
            dinv[node] = rsqrtf((float)(hist[t] + 1));
        }
    }
}

// ---------------- prep: W transposes to fp16 + gcur zero + dinv tail zero ----------------
__global__ __launch_bounds__(256) void k_prep(const float* __restrict__ W1,
                                              const float* __restrict__ W2,
                                              __half* __restrict__ w1t,
                                              __half* __restrict__ w2t,
                                              int* __restrict__ gcur,
                                              float* __restrict__ dinv) {
    int t = blockIdx.x * 256 + threadIdx.x;
    if (t < NBUCK) gcur[t] = 0;
    if (t < 128 * 256) {
        int n = t >> 8, k = t & 255;
        w1t[t] = __float2half(W1[k * NHID + n]);
    }
    if (t < 48 * 128) {
        int n = t >> 7, k = t & 127;
        w2t[t] = __float2half(n < NCLASS ? W2[k * NCLASS + n] : 0.0f);
    }
    if (t >= N_NODES && t < NPAD) dinv[t] = 0.0f;   // dummy rows scale to zero
}

// ---------------- GEMM1 (MFMA): h1h(fp16) = (x @ W1) * dinv[row]  (pre-scaled table) ----------------
#define G1_LDA 72
#define G1_LDB 72
#define G1_LDE 136
__global__ __launch_bounds__(256) void k_gemm1(const float* __restrict__ x,
                                               const __half* __restrict__ w1t,
                                               const float* __restrict__ dinv,
                                               __half* __restrict__ h1h) {
    __shared__ __half smem[64 * G1_LDA + 128 * G1_LDB];   // 27.6 KB
    __half* sA = smem;
    __half* sB = smem + 64 * G1_LDA;
    int t = threadIdx.x;
    int rbase = blockIdx.x * 64;
    int lane = t & 63, wv = t >> 6;
    int m = lane & 15, quad = lane >> 4;
    f32x4 acc[8];
    #pragma unroll
    for (int i = 0; i < 8; i++) acc[i] = (f32x4)0.0f;

    int arow = t >> 2, aseg = t & 3;
    int grow = rbase + arow;
    bool avalid = grow < N_NODES;
    int bn = t >> 1, bseg = t & 1;

    for (int k0 = 0; k0 < NFEAT; k0 += 64) {
        const float4* gs = (const float4*)(x + (size_t)grow * NFEAT + k0 + aseg * 16);
        __half* ad = sA + arow * G1_LDA + aseg * 16;
        #pragma unroll
        for (int i = 0; i < 4; i++) {
            float4 v = avalid ? gs[i] : make_float4(0.f, 0.f, 0.f, 0.f);
            __half2 h0 = __float22half2_rn(make_float2(v.x, v.y));
            __half2 h1 = __float22half2_rn(make_float2(v.z, v.w));
            uint2 st;
            st.x = __builtin_bit_cast(unsigned int, h0);
            st.y = __builtin_bit_cast(unsigned int, h1);
            *(uint2*)(ad + i * 4) = st;
        }
        const uint4* ws4 = (const uint4*)(w1t + bn * NFEAT + k0 + bseg * 32);
        uint4* bd = (uint4*)(sB + bn * G1_LDB + bseg * 32);
        #pragma unroll
        for (int i = 0; i < 4; i++) bd[i] = ws4[i];
        __syncthreads();
        #pragma unroll
        for (int kk = 0; kk < 64; kk += 32) {
            f16x8 af = *(const f16x8*)(sA + (wv * 16 + m) * G1_LDA + kk + quad * 8);
            #pragma unroll
            for (int t8 = 0; t8 < 8; t8++) {
                f16x8 bf = *(const f16x8*)(sB + (t8 * 16 + m) * G1_LDB + kk + quad * 8);
                acc[t8] = __builtin_amdgcn_mfma_f32_16x16x32_f16(af, bf, acc[t8], 0, 0, 0);
            }
        }
        __syncthreads();
    }
    // pre-scale each output row by dinv[row] while packing (rows >= N_NODES have dinv=0 -> zero rows)
    float di4[4];
    #pragma unroll
    for (int r = 0; r < 4; r++) di4[r] = dinv[rbase + wv * 16 + quad * 4 + r];
    __half* eb = smem;
    #pragma unroll
    for (int t8 = 0; t8 < 8; t8++) {
        #pragma unroll
        for (int r = 0; r < 4; r++)
            eb[(wv * 16 + quad * 4 + r) * G1_LDE + t8 * 16 + m] = __float2half(acc[t8][r] * di4[r]);
    }
    __syncthreads();
    {   // unconditional store: grid covers exactly NPAD rows; dummy rows are zeros
        const uint4* es = (const uint4*)(eb + arow * G1_LDE + aseg * 32);
        uint4* od = (uint4*)(h1h + (size_t)grow * NHID + aseg * 32);
        #pragma unroll
        for (int i = 0; i < 4; i++) od[i] = es[i];
    }
}

// ---------------- GEMM2 (MFMA): h2p(fp16, stride 64) = (h1p @ W2) * dinv[row] ----------------
#define G2_LDA 136
#define G2_LDB 136
#define G2_LDE 72
__global__ __launch_bounds__(256) void k_gemm2(const __half* __restrict__ h1p,
                                               const __half* __restrict__ w2t,
                                               const float* __restrict__ dinv,
                                               __half* __restrict__ h2p) {
    __shared__ __half smem[64 * G2_LDA + 48 * G2_LDB];  // 30.5 KB
    __half* sA = smem;
    __half* sB = smem + 64 * G2_LDA;
    int t = threadIdx.x;
    int rbase = blockIdx.x * 64;
    int lane = t & 63, wv = t >> 6;
    int m = lane & 15, quad = lane >> 4;
    f32x4 acc[3];
    #pragma unroll
    for (int i = 0; i < 3; i++) acc[i] = (f32x4)0.0f;

    int arow = t >> 2, aseg = t & 3;
    int grow = rbase + arow;
    bool avalid = grow < N_NODES;

    #pragma unroll
    for (int i = 0; i < 3; i++) {
        int idx = t + i * 256;
        int n = idx >> 4, seg = idx & 15;
        *(uint4*)(sB + n * G2_LDB + seg * 8) = *(const uint4*)(w2t + n * NHID + seg * 8);
    }
    {
        const uint4* gs = (const uint4*)(h1p + (size_t)grow * NHID + aseg * 32);
        uint4* ad = (uint4*)(sA + arow * G2_LDA + aseg * 32);
        uint4 z; z.x = z.y = z.z = z.w = 0;
        #pragma unroll
        for (int i = 0; i < 4; i++) ad[i] = avalid ? gs[i] : z;
    }
    __syncthreads();
    #pragma unroll
    for (int kk = 0; kk < 128; kk += 32) {
        f16x8 af = *(const f16x8*)(sA + (wv * 16 + m) * G2_LDA + kk + quad * 8);
        #pragma unroll
        for (int t3 = 0; t3 < 3; t3++) {
            f16x8 bf = *(const f16x8*)(sB + (t3 * 16 + m) * G2_LDB + kk + quad * 8);
            acc[t3] = __builtin_amdgcn_mfma_f32_16x16x32_f16(af, bf, acc[t3], 0, 0, 0);
        }
    }
    __syncthreads();
    float di4[4];
    #pragma unroll
    for (int r = 0; r < 4; r++) di4[r] = dinv[rbase + wv * 16 + quad * 4 + r];
    __half* eb = smem;
    #pragma unroll
    for (int t3 = 0; t3 < 3; t3++) {
        #pragma unroll
        for (int r = 0; r < 4; r++)
            eb[(wv * 16 + quad * 4 + r) * G2_LDE + t3 * 16 + m] = __float2half(acc[t3][r] * di4[r]);
    }
    {
        int zr = t >> 2, zc = 48 + (t & 3) * 4;
        uint2 z; z.x = z.y = 0;
        *(uint2*)(eb + zr * G2_LDE + zc) = z;
    }
    __syncthreads();
    #pragma unroll
    for (int i = 0; i < 2; i++) {
        int idx = t + i * 256;
        int row = idx >> 3, seg = idx & 7;
        int gr = rbase + row;   // unconditional: dummy rows store zeros (acc*0)
        *(uint4*)(h2p + (size_t)gr * 64 + seg * 8) = *(const uint4*)(eb + row * G2_LDE + seg * 8);
    }
}

__device__ __forceinline__ void acc8f(float* acc, uint4 v, float d) {
    float2 a0 = __half22float2(__builtin_bit_cast(__half2, v.x));
    float2 a1 = __half22float2(__builtin_bit_cast(__half2, v.y));
    float2 a2 = __half22float2(__builtin_bit_cast(__half2, v.z));
    float2 a3 = __half22float2(__builtin_bit_cast(__half2, v.w));
    acc[0] = fmaf(a0.x, d, acc[0]); acc[1] = fmaf(a0.y, d, acc[1]);
    acc[2] = fmaf(a1.x, d, acc[2]); acc[3] = fmaf(a1.y, d, acc[3]);
    acc[4] = fmaf(a2.x, d, acc[4]); acc[5] = fmaf(a2.y, d, acc[5]);
    acc[6] = fmaf(a3.x, d, acc[6]); acc[7] = fmaf(a3.y, d, acc[7]);
}

// ---------------- agg1: round-0 structure (64-thr, shuffle bcast) + pre-scaled table ----------------
// split-wave: 4 edge groups (q) x 16 row-chunk lanes (fl); 8-deep gathers; no dinv gather, pure adds
__global__ __launch_bounds__(64) void k_agg1(const __half* __restrict__ h1h,
                                             const float* __restrict__ dinv,
                                             const int* __restrict__ row_beg,
                                             const int* __restrict__ row_cnt,
                                             const int* __restrict__ esrc,
                                             const float* __restrict__ b1,
                                             const float* __restrict__ mask,
                                             __half* __restrict__ h1p) {
    int i = blockIdx.x;
    int lane = threadIdx.x;
    int q = lane >> 4;
    int fl = lane & 15;
    const uint4* hv4 = (const uint4*)h1h;
    float di = dinv[i];
    __half2 hacc[4];
    __half2 hz = __half2half2(__float2half(0.0f));
    hacc[0] = hz; hacc[1] = hz; hacc[2] = hz; hacc[3] = hz;
    int s0 = row_beg[i], cnt = row_cnt[i];
    for (int base = 0; base < cnt; base += 64) {
        int idx = base + lane;
        int sv = (idx < cnt) ? esrc[s0 + idx] : DUMMY;   // dummy row = zeros
        int n = min(64, cnt - base);
        int nr = (n + 31) & ~31;
        for (int j = 0; j < nr; j += 32) {
            int ss[8]; uint4 vv[8];
            #pragma unroll
            for (int k = 0; k < 8; k++) ss[k] = __shfl(sv, j + 4 * k + q);
            #pragma unroll
            for (int k = 0; k < 8; k++) vv[k] = hv4[(size_t)ss[k] * 16 + fl];
            #pragma unroll
            for (int k = 0; k < 8; k++) {
                hacc[0] = __hadd2(hacc[0], __builtin_bit_cast(__half2, vv[k].x));
                hacc[1] = __hadd2(hacc[1], __builtin_bit_cast(__half2, vv[k].y));
                hacc[2] = __hadd2(hacc[2], __builtin_bit_cast(__half2, vv[k].z));
                hacc[3] = __hadd2(hacc[3], __builtin_bit_cast(__half2, vv[k].w));
            }
        }
    }
    // reduce across the 4 edge groups in half2 (strides 16, 32)
    #pragma unroll
    for (int d = 16; d <= 32; d <<= 1) {
        #pragma unroll
        for (int r = 0; r < 4; r++) {
            unsigned int u = __shfl_xor(__builtin_bit_cast(unsigned int, hacc[r]), d);
            hacc[r] = __hadd2(hacc[r], __builtin_bit_cast(__half2, u));
        }
    }
    if (q == 0) {
        float acc[8];
        #pragma unroll
        for (int r = 0; r < 4; r++) {
            float2 f = __half22float2(hacc[r]);
            acc[2 * r] = f.x; acc[2 * r + 1] = f.y;
        }
        uint4 sv4 = hv4[(size_t)i * 16 + fl];      // self row (already *dinv[i])
        acc8f(acc, sv4, 1.0f);
        float4 bb0 = ((const float4*)b1)[fl * 2];
        float4 bb1 = ((const float4*)b1)[fl * 2 + 1];
        const float4* mrow = (const float4*)(mask + (size_t)i * NHID);
        float4 mm0 = mrow[fl * 2];
        float4 mm1 = mrow[fl * 2 + 1];
        float o0 = fmaxf(fmaf(acc[0], di, bb0.x), 0.f) * mm0.x;
        float o1 = fmaxf(fmaf(acc[1], di, bb0.y), 0.f) * mm0.y;
        float o2 = fmaxf(fmaf(acc[2], di, bb0.z), 0.f) * mm0.z;
        float o3 = fmaxf(fmaf(acc[3], di, bb0.w), 0.f) * mm0.w;
        float o4 = fmaxf(fmaf(acc[4], di, bb1.x), 0.f) * mm1.x;
        float o5 = fmaxf(fmaf(acc[5], di, bb1.y), 0.f) * mm1.y;
        float o6 = fmaxf(fmaf(acc[6], di, bb1.z), 0.f) * mm1.z;
        float o7 = fmaxf(fmaf(acc[7], di, bb1.w), 0.f) * mm1.w;
        __half2 p0 = __float22half2_rn(make_float2(o0, o1));
        __half2 p1 = __float22half2_rn(make_float2(o2, o3));
        __half2 p2 = __float22half2_rn(make_float2(o4, o5));
        __half2 p3 = __float22half2_rn(make_float2(o6, o7));
        uint4 st;
        st.x = __builtin_bit_cast(unsigned int, p0);
        st.y = __builtin_bit_cast(unsigned int, p1);
        st.z = __builtin_bit_cast(unsigned int, p2);
        st.w = __builtin_bit_cast(unsigned int, p3);
        ((uint4*)h1p)[(size_t)i * 16 + fl] = st;
    }
}

// ---------------- agg2 + bias + log_softmax: round-0 structure + pre-scaled table ----------------
__global__ __launch_bounds__(64) void k_agg2(const __half* __restrict__ h2p,
                                             const float* __restrict__ dinv,
                                             const int* __restrict__ row_beg,
                                             const int* __restrict__ row_cnt,
                                             const int* __restrict__ esrc,
                                             const float* __restrict__ b2,
                                             float* __restrict__ out) {
    int i = blockIdx.x;
    int lane = threadIdx.x;
    int o8 = lane >> 3;
    int fl = lane & 7;
    const uint4* hv4 = (const uint4*)h2p;
    float di = dinv[i];
    __half2 hacc[4];
    __half2 hz = __half2half2(__float2half(0.0f));
    hacc[0] = hz; hacc[1] = hz; hacc[2] = hz; hacc[3] = hz;
    int s0 = row_beg[i], cnt = row_cnt[i];
    for (int base = 0; base < cnt; base += 64) {
        int idx = base + lane;
        int sv = (idx < cnt) ? esrc[s0 + idx] : DUMMY;
        int n = min(64, cnt - base);
        int nr = (n + 31) & ~31;
        for (int j = 0; j < nr; j += 32) {
            int ss[4]; uint4 vv[4];
            #pragma unroll
            for (int k = 0; k < 4; k++) ss[k] = __shfl(sv, j + 8 * k + o8);
            #pragma unroll
            for (int k = 0; k < 4; k++) vv[k] = hv4[(size_t)ss[k] * 8 + fl];
            #pragma unroll
            for (int k = 0; k < 4; k++) {
                hacc[0] = __hadd2(hacc[0], __builtin_bit_cast(__half2, vv[k].x));
                hacc[1] = __hadd2(hacc[1], __builtin_bit_cast(__half2, vv[k].y));
                hacc[2] = __hadd2(hacc[2], __builtin_bit_cast(__half2, vv[k].z));
                hacc[3] = __hadd2(hacc[3], __builtin_bit_cast(__half2, vv[k].w));
            }
        }
    }
    // reduce across the 8 edge groups in half2 (strides 8, 16, 32)
    #pragma unroll
    for (int d = 8; d <= 32; d <<= 1) {
        #pragma unroll
        for (int r = 0; r < 4; r++) {
            unsigned int u = __shfl_xor(__builtin_bit_cast(unsigned int, hacc[r]), d);
            hacc[r] = __hadd2(hacc[r], __builtin_bit_cast(__half2, u));
        }
    }
    if (o8 == 0) {
        bool act = (fl < 5);
        float acc[8];
        #pragma unroll
        for (int r = 0; r < 4; r++) {
            float2 f = __half22float2(hacc[r]);
            acc[2 * r] = f.x; acc[2 * r + 1] = f.y;
        }
        uint4 sv4 = hv4[(size_t)i * 8 + fl];       // self row (already *dinv[i])
        acc8f(acc, sv4, 1.0f);
        float val[8];
        float m = -INFINITY;
        if (act) {
            float4 bb0 = ((const float4*)b2)[fl * 2];
            float4 bb1 = ((const float4*)b2)[fl * 2 + 1];
            val[0] = fmaf(acc[0], di, bb0.x);
            val[1] = fmaf(acc[1], di, bb0.y);
            val[2] = fmaf(acc[2], di, bb0.z);
            val[3] = fmaf(acc[3], di, bb0.w);
            val[4] = fmaf(acc[4], di, bb1.x);
            val[5] = fmaf(acc[5], di, bb1.y);
            val[6] = fmaf(acc[6], di, bb1.z);
            val[7] = fmaf(acc[7], di, bb1.w);
            #pragma unroll
            for (int k = 0; k < 8; k++) m = fmaxf(m, val[k]);
        }
        m = fmaxf(m, __shfl_xor(m, 1));
        m = fmaxf(m, __shfl_xor(m, 2));
        m = fmaxf(m, __shfl_xor(m, 4));
        float ss = 0.f;
        if (act) {
            #pragma unroll
            for (int k = 0; k < 8; k++) ss += expf(val[k] - m);
        }
        ss += __shfl_xor(ss, 1);
        ss += __shfl_xor(ss, 2);
        ss += __shfl_xor(ss, 4);
        if (act) {
            float ls = m + logf(ss);
            float4 r0 = make_float4(val[0] - ls, val[1] - ls, val[2] - ls, val[3] - ls);
            float4 r1 = make_float4(val[4] - ls, val[5] - ls, val[6] - ls, val[7] - ls);
            float4* orow = (float4*)(out + (size_t)i * NCLASS + fl * 8);
            orow[0] = r0;
            orow[1] = r1;
        }
    }
}

extern "C" void kernel_launch(void* const* d_in, const int* in_sizes, int n_in,
                              void* d_out, int out_size, void* d_ws, size_t ws_size,
                              hipStream_t stream) {
    const float* x    = (const float*)d_in[0];
    const int*   ei   = (const int*)d_in[1];
    const float* W1   = (const float*)d_in[2];
    const float* b1   = (const float*)d_in[3];
    const float* W2   = (const float*)d_in[4];
    const float* b2   = (const float*)d_in[5];
    const float* mask = (const float*)d_in[6];
    float* out = (float*)d_out;

    const int* src = ei;
    const int* dst = ei + N_EDGES;

    char* ws = (char*)d_ws;
    size_t off = 0;
    __half* h1p    = (__half*)(ws + off); off += (size_t)NPAD * NHID * 2;      // 12.8 MB (incl. dummy rows)
    __half* h1h    = (__half*)(ws + off); off += (size_t)NPAD * NHID * 2;      // 12.8 MB
    int*    esrc   = (int*)   (ws + off); off += (size_t)NBUCK * CAP * 4 + 256;// 8.0 MB (+tail pad)
    float*  dinv   = (float*) (ws + off); off += 200192;
    int*   row_beg = (int*)   (ws + off); off += 200192;
    int*   row_cnt = (int*)   (ws + off); off += 200192;
    int*   gcur    = (int*)   (ws + off); off += 2048;
    __half* w1t    = (__half*)(ws + off); off += 128 * 256 * 2;                // 64 KB
    __half* w2t    = (__half*)(ws + off); off += 48 * 128 * 2;                 // 12 KB

    unsigned int* packed = (unsigned int*)h1p;  // binA/binB lifetime only
    __half* h2p = h1h;                           // gemm2/agg2 lifetime only (6.4 MB used)

    k_prep<<<196, 256, 0, stream>>>(W1, W2, w1t, w2t, gcur, dinv);
    k_binA<<<(N_EDGES + EPB - 1) / EPB, 256, 0, stream>>>(src, dst, gcur, packed);
    k_binB<<<NBUCK, 256, 0, stream>>>(gcur, packed, esrc, row_beg, row_cnt, dinv);

    k_gemm1<<<NPAD / 64, 256, 0, stream>>>(x, w1t, dinv, h1h);
    k_agg1<<<N_NODES, 64, 0, stream>>>(h1h, dinv, row_beg, row_cnt, esrc, b1, mask, h1p);
    k_gemm2<<<NPAD / 64, 256, 0, stream>>>(h1p, w2t, dinv, h2p);
    k_agg2<<<N_NODES, 64, 0, stream>>>(h2p, dinv, row_beg, row_cnt, esrc, b2, out);
}